// Round 14
// baseline (1000.838 us; speedup 1.0000x reference)
//
#include <hip/hip_runtime.h>

// WRGCN: out[t] = sum_r (sum_{e:tgt=t,rel=r} ew_e * X[src_e]) @ W_r + X[t] @ W_self + P @ bias
// Counting-sort edges by key = r*N + tgt. k_main: 512 thr / 64 targets; wave w owns keys
// [n0+8w, n0+8w+8). PAIRED-RELATION phases: As[64][512] holds 2 rels; per phase issue 16
// gathers (2 rels) -> K=512 MFMA (covers latency) -> barrier -> zero+finish -> barrier.
// 4 phases instead of 8. NOTE: k_main needs ~100-128 VGPR; (512,4) caps at 128 (2 blk/CU).

#define N_ENT 200000
#define D 256
#define R_REL 8
#define E_EDGE 150000
#define TOT_E (R_REL * E_EDGE)        // 1,200,000
#define MKEY (N_ENT * R_REL)          // 1,600,000
#define SCAN_B 1024
#define NBLK_SCAN ((MKEY + SCAN_B - 1) / SCAN_B)   // 1563

typedef __bf16 bf16x8 __attribute__((ext_vector_type(8)));
typedef unsigned short u16x8 __attribute__((ext_vector_type(8)));
typedef float f32x4 __attribute__((ext_vector_type(4)));

__device__ __forceinline__ unsigned short f2bf(float f) {
  unsigned int u = __builtin_bit_cast(unsigned int, f);
  u += 0x7FFFu + ((u >> 16) & 1u);   // RNE (inputs finite)
  return (unsigned short)(u >> 16);
}
__device__ __forceinline__ float bf2f(unsigned short u) {
  return __builtin_bit_cast(float, ((unsigned)u) << 16);
}
__device__ __forceinline__ f32x4 mfma16(u16x8 a, u16x8 b, f32x4 c) {
  return __builtin_amdgcn_mfma_f32_16x16x32_bf16(
      __builtin_bit_cast(bf16x8, a), __builtin_bit_cast(bf16x8, b), c, 0, 0, 0);
}

// ---- X (f32) -> Xh (bf16), fused with edge-target histogram ----
__global__ __launch_bounds__(256) void k_cvt_x(const float* __restrict__ x,
                                               unsigned short* __restrict__ xh,
                                               const int* __restrict__ ei,
                                               unsigned* __restrict__ counts) {
  int i = blockIdx.x * 256 + threadIdx.x;
  const float4* xv = (const float4*)x;
  float4 a = xv[2 * i], b = xv[2 * i + 1];
  uint4 o;
  o.x = (unsigned)f2bf(a.x) | ((unsigned)f2bf(a.y) << 16);
  o.y = (unsigned)f2bf(a.z) | ((unsigned)f2bf(a.w) << 16);
  o.z = (unsigned)f2bf(b.x) | ((unsigned)f2bf(b.y) << 16);
  o.w = (unsigned)f2bf(b.z) | ((unsigned)f2bf(b.w) << 16);
  ((uint4*)xh)[i] = o;
  if (i < TOT_E) {
    int r = i / E_EDGE, e = i - r * E_EDGE;
    int tgt = ei[(r * 2 + 1) * E_EDGE + e];
    atomicAdd(&counts[r * N_ENT + tgt], 1u);
  }
}

// ---- Weights -> bf16 MFMA B-fragment order (blocks 0..287); bias frag (blocks 288..291) ----
__global__ __launch_bounds__(256) void k_cvt_w(const float* __restrict__ relw,
                                               const float* __restrict__ selfw,
                                               const float* __restrict__ bias,
                                               unsigned short* __restrict__ wf,
                                               unsigned short* __restrict__ bb) {
  if (blockIdx.x < 288) {
    int t = blockIdx.x * 256 + threadIdx.x;   // 9*8*16*64 = 73728
    int rel = t >> 13;
    int rem = t & 8191;
    int kb = rem >> 10;
    int nb = (rem >> 6) & 15;
    int lane = rem & 63;
    const float* W = (rel < R_REL) ? (relw + rel * D * D) : selfw;
    int k0 = kb * 32 + (lane >> 4) * 8;
    int n = nb * 16 + (lane & 15);
    unsigned int o[4];
#pragma unroll
    for (int jj = 0; jj < 4; ++jj) {
      unsigned lo = f2bf(W[(k0 + 2 * jj) * D + n]);
      unsigned hi = f2bf(W[(k0 + 2 * jj + 1) * D + n]);
      o[jj] = lo | (hi << 16);
    }
    ((uint4*)wf)[t] = make_uint4(o[0], o[1], o[2], o[3]);
  } else {
    int t = (blockIdx.x - 288) * 256 + threadIdx.x;   // 1024
    int nb = t >> 6, lane = t & 63;
    int lk = lane >> 4, n = nb * 16 + (lane & 15);
    unsigned int o[4];
#pragma unroll
    for (int jj = 0; jj < 4; ++jj) {
      unsigned lo = 0, hi = 0;
      if (lk == 0) {
        lo = f2bf(bias[(2 * jj) * D + n]);
        hi = f2bf(bias[(2 * jj + 1) * D + n]);
      }
      o[jj] = lo | (hi << 16);
    }
    ((uint4*)bb)[t] = make_uint4(o[0], o[1], o[2], o[3]);
  }
}

// ---- exclusive scan (3 kernels) ----
__global__ __launch_bounds__(256) void k_scan1(const unsigned* __restrict__ cnt,
                                               unsigned* __restrict__ off,
                                               unsigned* __restrict__ aux) {
  __shared__ unsigned sc[256];
  int tid = threadIdx.x;
  int base = blockIdx.x * SCAN_B + tid * 4;
  unsigned v[4];
#pragma unroll
  for (int j = 0; j < 4; ++j) v[j] = (base + j < MKEY) ? cnt[base + j] : 0u;
  unsigned s = v[0] + v[1] + v[2] + v[3];
  sc[tid] = s;
  __syncthreads();
  for (int o = 1; o < 256; o <<= 1) {
    unsigned t = (tid >= o) ? sc[tid - o] : 0u;
    __syncthreads();
    sc[tid] += t;
    __syncthreads();
  }
  unsigned excl = sc[tid] - s;
  if (tid == 255) aux[blockIdx.x] = sc[255];
#pragma unroll
  for (int j = 0; j < 4; ++j) {
    if (base + j < MKEY) off[base + j] = excl;
    excl += v[j];
  }
}

__global__ __launch_bounds__(256) void k_scan2(unsigned* __restrict__ aux) {
  __shared__ unsigned sc[256];
  int tid = threadIdx.x;
  int base = tid * 7;
  unsigned v[7];
#pragma unroll
  for (int j = 0; j < 7; ++j) v[j] = (base + j < NBLK_SCAN) ? aux[base + j] : 0u;
  unsigned s = 0;
#pragma unroll
  for (int j = 0; j < 7; ++j) s += v[j];
  sc[tid] = s;
  __syncthreads();
  for (int o = 1; o < 256; o <<= 1) {
    unsigned t = (tid >= o) ? sc[tid - o] : 0u;
    __syncthreads();
    sc[tid] += t;
    __syncthreads();
  }
  unsigned excl = sc[tid] - s;
#pragma unroll
  for (int j = 0; j < 7; ++j) {
    if (base + j < NBLK_SCAN) aux[base + j] = excl;
    excl += v[j];
  }
}

__global__ __launch_bounds__(256) void k_scan3(unsigned* __restrict__ off,
                                               const unsigned* __restrict__ aux) {
  unsigned add = aux[blockIdx.x];
  int base = blockIdx.x * SCAN_B + threadIdx.x * 4;
  if (base + 3 < MKEY) {
    uint4* p = (uint4*)(off + base);
    uint4 x = *p;
    x.x += add; x.y += add; x.z += add; x.w += add;
    *p = x;
  } else {
    for (int j = 0; j < 4; ++j)
      if (base + j < MKEY) off[base + j] += add;
  }
}

// ---- scatter (src | (tgt&63)<<18, ew); off becomes segment ENDs ----
__global__ __launch_bounds__(256) void k_scatter(const int* __restrict__ ei,
                                                 const float* __restrict__ ew,
                                                 unsigned* __restrict__ off,
                                                 unsigned* __restrict__ spack,
                                                 float* __restrict__ sewt) {
  int t = blockIdx.x * 256 + threadIdx.x;
  if (t >= TOT_E) return;
  int r = t / E_EDGE, e = t - r * E_EDGE;
  int tgt = ei[(r * 2 + 1) * E_EDGE + e];
  int src = ei[(r * 2) * E_EDGE + e];
  float w = ew[t];
  unsigned pos = atomicAdd(&off[r * N_ENT + tgt], 1u);
  spack[pos] = (unsigned)src | ((unsigned)(tgt & 63) << 18);
  sewt[pos] = w;
}

// ---- issue 16 gathers for a relation pair (addresses via shfl; pk not kept) ----
__device__ __forceinline__ void agg2_issue(int lane,
                                           unsigned sLo, unsigned eLo, unsigned pkcLo,
                                           unsigned sHi, unsigned eHi, unsigned pkcHi,
                                           const unsigned short* __restrict__ xh,
                                           ushort4 xv[16]) {
  int mLo = (int)(eLo - sLo); mLo = mLo < 8 ? mLo : 8;
  int mHi = (int)(eHi - sHi); mHi = mHi < 8 ? mHi : 8;
#pragma unroll
  for (int u = 0; u < 8; ++u) {
    unsigned pk = (unsigned)__shfl((int)pkcLo, u);
    unsigned srcu = (u < mLo) ? (pk & 0x3FFFFu) : 0u;   // invalid -> row 0 (L1-hot)
    xv[u] = *(const ushort4*)(xh + (size_t)srcu * 256 + lane * 4);
  }
#pragma unroll
  for (int u = 0; u < 8; ++u) {
    unsigned pk = (unsigned)__shfl((int)pkcHi, u);
    unsigned srcu = (u < mHi) ? (pk & 0x3FFFFu) : 0u;
    xv[8 + u] = *(const ushort4*)(xh + (size_t)srcu * 256 + lane * 4);
  }
}

// ---- finish one relation half: run-length accumulate + flush (stride 1024, +halfOff) ----
__device__ __forceinline__ void agg_fin_half(int lane, unsigned s0, unsigned e0,
                                             unsigned pkc, float wtc,
                                             const unsigned* __restrict__ spack,
                                             const float* __restrict__ sewt,
                                             const unsigned short* __restrict__ xh,
                                             unsigned char* As, int halfOff,
                                             const ushort4* xv) {
  int total = (int)(e0 - s0);
  if (total <= 0) return;
  int gp = -1;
  float a0 = 0.f, a1 = 0.f, a2 = 0.f, a3 = 0.f;
#define AGG_FLUSH2() do { \
    unsigned lo_ = (unsigned)f2bf(a0) | ((unsigned)f2bf(a1) << 16); \
    unsigned hi_ = (unsigned)f2bf(a2) | ((unsigned)f2bf(a3) << 16); \
    int wb_ = (gp * 1024 + halfOff + lane * 8) ^ ((gp & 7) << 4); \
    *(uint2*)(As + wb_) = make_uint2(lo_, hi_); } while (0)

  int mch = total < 64 ? total : 64;
  int m0 = mch < 8 ? mch : 8;
  // group 0: gathers prefetched in agg2_issue
#pragma unroll
  for (int u = 0; u < 8; ++u) {
    if (u < m0) {
      unsigned pk = (unsigned)__shfl((int)pkc, u);
      float wt = __shfl(wtc, u);
      int g = (int)(pk >> 18);
      if (g != gp) {
        if (gp >= 0) AGG_FLUSH2();
        a0 = a1 = a2 = a3 = 0.f;
        gp = g;
      }
      a0 += wt * bf2f(xv[u].x);
      a1 += wt * bf2f(xv[u].y);
      a2 += wt * bf2f(xv[u].z);
      a3 += wt * bf2f(xv[u].w);
    }
  }
  // remaining groups of chunk 0 (rare: >8 edges in an 8-key segment)
  for (int g8 = 8; g8 < mch; g8 += 8) {
    unsigned q8[8];
    float v8[8];
#pragma unroll
    for (int u = 0; u < 8; ++u) {
      q8[u] = (unsigned)__shfl((int)pkc, g8 + u);
      v8[u] = __shfl(wtc, g8 + u);
    }
    ushort4 yv[8];
#pragma unroll
    for (int u = 0; u < 8; ++u) {
      unsigned srcu = (g8 + u < mch) ? (q8[u] & 0x3FFFFu) : 0u;
      yv[u] = *(const ushort4*)(xh + (size_t)srcu * 256 + lane * 4);
    }
#pragma unroll
    for (int u = 0; u < 8; ++u) {
      if (g8 + u < mch) {
        int g = (int)(q8[u] >> 18);
        if (g != gp) {
          if (gp >= 0) AGG_FLUSH2();
          a0 = a1 = a2 = a3 = 0.f;
          gp = g;
        }
        float wt = v8[u];
        a0 += wt * bf2f(yv[u].x);
        a1 += wt * bf2f(yv[u].y);
        a2 += wt * bf2f(yv[u].z);
        a3 += wt * bf2f(yv[u].w);
      }
    }
  }
  // remaining chunks (very rare: >64 edges)
  for (unsigned chunk = s0 + 64u; chunk < e0; chunk += 64u) {
    unsigned idx = chunk + (unsigned)lane;
    if (idx >= (unsigned)TOT_E) idx = (unsigned)(TOT_E - 1);
    unsigned pkv = spack[idx];
    float wtv = sewt[idx];
    int rem = (int)(e0 - chunk);
    int m = rem < 64 ? rem : 64;
    for (int g8 = 0; g8 < m; g8 += 8) {
      unsigned q8[8];
      float v8[8];
#pragma unroll
      for (int u = 0; u < 8; ++u) {
        q8[u] = (unsigned)__shfl((int)pkv, g8 + u);
        v8[u] = __shfl(wtv, g8 + u);
      }
      ushort4 yv[8];
#pragma unroll
      for (int u = 0; u < 8; ++u) {
        unsigned srcu = (g8 + u < m) ? (q8[u] & 0x3FFFFu) : 0u;
        yv[u] = *(const ushort4*)(xh + (size_t)srcu * 256 + lane * 4);
      }
#pragma unroll
      for (int u = 0; u < 8; ++u) {
        if (g8 + u < m) {
          int g = (int)(q8[u] >> 18);
          if (g != gp) {
            if (gp >= 0) AGG_FLUSH2();
            a0 = a1 = a2 = a3 = 0.f;
            gp = g;
          }
          float wt = v8[u];
          a0 += wt * bf2f(yv[u].x);
          a1 += wt * bf2f(yv[u].y);
          a2 += wt * bf2f(yv[u].z);
          a3 += wt * bf2f(yv[u].w);
        }
      }
    }
  }
  if (gp >= 0) AGG_FLUSH2();
#undef AGG_FLUSH2
}

// ---- fused main: 512 threads / 64 targets, paired-rel phases, As[64][512] bf16 ----
__global__ __launch_bounds__(512, 4) void k_main(const unsigned short* __restrict__ xh,
                                                 const unsigned short* __restrict__ wf,
                                                 const unsigned short* __restrict__ bbf,
                                                 const unsigned* __restrict__ counts,
                                                 const unsigned* __restrict__ off_end,
                                                 const unsigned* __restrict__ spack,
                                                 const float* __restrict__ sewt,
                                                 float* __restrict__ out) {
  __shared__ __align__(16) unsigned char As[64 * 1024];   // [64 rows][512 cols bf16]
  int n0 = blockIdx.x * 64;
  int tid = threadIdx.x;
  int w = tid >> 6, lane = tid & 63;
  int lm = lane & 15, lk = lane >> 4;
  int rbase = (w >> 2) * 32;          // wave's 32-row half for MFMA
  int cbase = (w & 3) * 4;            // wave's 4 nb columns (64 cols)
  int g0 = w * 8;                     // wave's first owned row

  // ---- prefetch 1: all 8 rels' segment bounds (16 independent loads) ----
  unsigned sB[8], eE[8];
#pragma unroll
  for (int r = 0; r < 8; ++r) {
    int kb2 = r * N_ENT + n0 + w * 8;
    sB[r] = kb2 ? off_end[kb2 - 1] : 0u;
    eE[r] = off_end[kb2 + 7];
  }

  f32x4 acc[2][4] = {};

  // ---- self phase (hides meta latency): A-frags direct from global bf16 X ----
  {
    const unsigned short* wfb = wf + 8 * 65536;
#pragma unroll
    for (int kb = 0; kb < 8; ++kb) {
      u16x8 a[2], b[4];
#pragma unroll
      for (int mi = 0; mi < 2; ++mi)
        a[mi] = *(const u16x8*)(xh + (size_t)(n0 + rbase + mi * 16 + lm) * 256 + kb * 32 + lk * 8);
#pragma unroll
      for (int ni = 0; ni < 4; ++ni)
        b[ni] = *(const u16x8*)(wfb + ((kb * 16 + cbase + ni) * 64 + lane) * 8);
#pragma unroll
      for (int mi = 0; mi < 2; ++mi)
#pragma unroll
        for (int ni = 0; ni < 4; ++ni)
          acc[mi][ni] = mfma16(a[mi], b[ni], acc[mi][ni]);
    }
  }

  // ---- prefetch 2: first 64-edge chunk per rel (16 independent loads) ----
  unsigned pk0[8];
  float wt0[8];
#pragma unroll
  for (int r = 0; r < 8; ++r) {
    unsigned idx = sB[r] + (unsigned)lane;
    if (idx >= (unsigned)TOT_E) idx = (unsigned)(TOT_E - 1);
    pk0[r] = spack[idx];
    wt0[r] = sewt[idx];
  }

  f32x4 z4 = {0.f, 0.f, 0.f, 0.f};

  // ---- prologue: aggregate rels 0,1 into As ----
  {
    ushort4 xv[16];
    agg2_issue(lane, sB[0], eE[0], pk0[0], sB[1], eE[1], pk0[1], xh, xv);
#pragma unroll
    for (int k = 0; k < 8; ++k) {
      int g = g0 + k;
      int wb = (g * 1024 + lane * 16) ^ ((g & 7) << 4);
      *(f32x4*)(As + wb) = z4;
    }
    agg_fin_half(lane, sB[0], eE[0], pk0[0], wt0[0], spack, sewt, xh, As, 0, xv);
    agg_fin_half(lane, sB[1], eE[1], pk0[1], wt0[1], spack, sewt, xh, As, 512, xv + 8);
  }
  __syncthreads();

  // ---- 4 paired-relation phases ----
#pragma unroll
  for (int p = 0; p < 4; ++p) {
    ushort4 xv[16];
    if (p < 3)
      agg2_issue(lane, sB[2 * p + 2], eE[2 * p + 2], pk0[2 * p + 2],
                 sB[2 * p + 3], eE[2 * p + 3], pk0[2 * p + 3], xh, xv);

    // MFMA K=512 over rel pair (2p, 2p+1) — covers the just-issued gathers
    const unsigned short* wfbL = wf + (2 * p) * 65536;
    const unsigned short* wfbR = wf + (2 * p + 1) * 65536;
#pragma unroll
    for (int kb2 = 0; kb2 < 16; ++kb2) {
      const unsigned short* wfb = (kb2 < 8) ? wfbL : wfbR;
      int kb = kb2 & 7;
      u16x8 a[2], b[4];
#pragma unroll
      for (int mi = 0; mi < 2; ++mi) {
        int row = rbase + mi * 16 + lm;
        int byt = (row * 1024 + kb2 * 64 + lk * 16) ^ ((row & 7) << 4);
        a[mi] = *(const u16x8*)(As + byt);
      }
#pragma unroll
      for (int ni = 0; ni < 4; ++ni)
        b[ni] = *(const u16x8*)(wfb + ((kb * 16 + cbase + ni) * 64 + lane) * 8);
#pragma unroll
      for (int mi = 0; mi < 2; ++mi)
#pragma unroll
        for (int ni = 0; ni < 4; ++ni)
          acc[mi][ni] = mfma16(a[mi], b[ni], acc[mi][ni]);
    }

    if (p < 3) {
      __syncthreads();   // all MFMA reads of As complete
#pragma unroll
      for (int k = 0; k < 8; ++k) {
        int g = g0 + k;
        int wb = (g * 1024 + lane * 16) ^ ((g & 7) << 4);
        *(f32x4*)(As + wb) = z4;
      }
      agg_fin_half(lane, sB[2 * p + 2], eE[2 * p + 2], pk0[2 * p + 2], wt0[2 * p + 2],
                   spack, sewt, xh, As, 0, xv);
      agg_fin_half(lane, sB[2 * p + 3], eE[2 * p + 3], pk0[2 * p + 3], wt0[2 * p + 3],
                   spack, sewt, xh, As, 512, xv + 8);
      __syncthreads();   // writes done before next MFMA
    }
  }

  // ---- bias via presence MFMA: P[64x8] @ bias[8x256] ----
  {
    u16x8 bb[4];
#pragma unroll
    for (int ni = 0; ni < 4; ++ni)
      bb[ni] = *(const u16x8*)(bbf + ((cbase + ni) * 64 + lane) * 8);
#pragma unroll
    for (int mi = 0; mi < 2; ++mi) {
      u16x8 pa = {};
      if (lk == 0) {
        int n = n0 + rbase + mi * 16 + lm;
#pragma unroll
        for (int r = 0; r < 8; ++r)
          pa[r] = counts[r * N_ENT + n] ? 0x3F80 : 0;
      }
#pragma unroll
      for (int ni = 0; ni < 4; ++ni)
        acc[mi][ni] = mfma16(pa, bb[ni], acc[mi][ni]);
    }
  }

  // ---- epilogue ----
#pragma unroll
  for (int mi = 0; mi < 2; ++mi)
#pragma unroll
    for (int ni = 0; ni < 4; ++ni) {
      int col = (w & 3) * 64 + ni * 16 + lm;
#pragma unroll
      for (int j = 0; j < 4; ++j) {
        int row = n0 + rbase + mi * 16 + lk * 4 + j;
        out[row * 256 + col] = acc[mi][ni][j];
      }
    }
}

extern "C" void kernel_launch(void* const* d_in, const int* in_sizes, int n_in,
                              void* d_out, int out_size, void* d_ws, size_t ws_size,
                              hipStream_t stream) {
  const float* x = (const float*)d_in[0];
  const float* relw = (const float*)d_in[1];
  const float* selfw = (const float*)d_in[2];
  const float* bias = (const float*)d_in[3];
  const int* ei = (const int*)d_in[4];
  const float* ew = (const float*)d_in[5];
  float* out = (float*)d_out;

  char* ws = (char*)d_ws;
  unsigned short* xh = (unsigned short*)ws;                          // 102,400,000
  unsigned short* wf = (unsigned short*)(ws + 102400000);            //   1,179,648
  unsigned short* bbf = (unsigned short*)(ws + 103579648);           //      16,384
  unsigned* counts = (unsigned*)(ws + 103596032);                    //   6,400,000
  unsigned* offs = (unsigned*)(ws + 109996032);                      //   6,400,000
  unsigned* aux = (unsigned*)(ws + 116396032);                       //       8,192
  unsigned* spack = (unsigned*)(ws + 116404224);                     //   4,800,000
  float* sewt = (float*)(ws + 121204224);                            //   4,800,000

  hipMemsetAsync(counts, 0, (size_t)MKEY * 4, stream);
  k_cvt_x<<<(N_ENT * D) / 2048, 256, 0, stream>>>(x, xh, ei, counts);   // + fused hist
  k_cvt_w<<<292, 256, 0, stream>>>(relw, selfw, bias, wf, bbf);         // + fused bias cvt
  k_scan1<<<NBLK_SCAN, 256, 0, stream>>>(counts, offs, aux);
  k_scan2<<<1, 256, 0, stream>>>(aux);
  k_scan3<<<NBLK_SCAN, 256, 0, stream>>>(offs, aux);
  k_scatter<<<(TOT_E + 255) / 256, 256, 0, stream>>>(ei, ew, offs, spack, sewt);
  k_main<<<N_ENT / 64, 512, 0, stream>>>(xh, wf, bbf, counts, offs, spack, sewt, out);
}

// Round 15
// 730.906 us; speedup vs baseline: 1.3693x; 1.3693x over previous
//
#include <hip/hip_runtime.h>

// WRGCN: out[t] = sum_r (sum_{e:tgt=t,rel=r} ew_e * X[src_e]) @ W_r + X[t] @ W_self + P @ bias
// Counting-sort edges by key = r*N + tgt. k_main: 512 thr / 64 targets; wave w owns keys
// [n0+8w, n0+8w+8). PAIRED-RELATION phases: As[64][512] holds 2 rels; per phase issue 16
// gathers (2 rels) -> K=512 MFMA (covers latency) -> barrier -> zero+finish -> barrier.
// VGPR NOTE (r12/r14 lesson): __launch_bounds__(B,N) caps VGPR at 256/N on this toolchain.
// N=4 -> 64-reg cap -> catastrophic spills. Use N=2 (128 cap); kernel needs ~110-130.

#define N_ENT 200000
#define D 256
#define R_REL 8
#define E_EDGE 150000
#define TOT_E (R_REL * E_EDGE)        // 1,200,000
#define MKEY (N_ENT * R_REL)          // 1,600,000
#define SCAN_B 1024
#define NBLK_SCAN ((MKEY + SCAN_B - 1) / SCAN_B)   // 1563

typedef __bf16 bf16x8 __attribute__((ext_vector_type(8)));
typedef unsigned short u16x8 __attribute__((ext_vector_type(8)));
typedef float f32x4 __attribute__((ext_vector_type(4)));

__device__ __forceinline__ unsigned short f2bf(float f) {
  unsigned int u = __builtin_bit_cast(unsigned int, f);
  u += 0x7FFFu + ((u >> 16) & 1u);   // RNE (inputs finite)
  return (unsigned short)(u >> 16);
}
__device__ __forceinline__ float bf2f(unsigned short u) {
  return __builtin_bit_cast(float, ((unsigned)u) << 16);
}
__device__ __forceinline__ f32x4 mfma16(u16x8 a, u16x8 b, f32x4 c) {
  return __builtin_amdgcn_mfma_f32_16x16x32_bf16(
      __builtin_bit_cast(bf16x8, a), __builtin_bit_cast(bf16x8, b), c, 0, 0, 0);
}

// ---- X (f32) -> Xh (bf16), fused with edge-target histogram ----
__global__ __launch_bounds__(256) void k_cvt_x(const float* __restrict__ x,
                                               unsigned short* __restrict__ xh,
                                               const int* __restrict__ ei,
                                               unsigned* __restrict__ counts) {
  int i = blockIdx.x * 256 + threadIdx.x;
  const float4* xv = (const float4*)x;
  float4 a = xv[2 * i], b = xv[2 * i + 1];
  uint4 o;
  o.x = (unsigned)f2bf(a.x) | ((unsigned)f2bf(a.y) << 16);
  o.y = (unsigned)f2bf(a.z) | ((unsigned)f2bf(a.w) << 16);
  o.z = (unsigned)f2bf(b.x) | ((unsigned)f2bf(b.y) << 16);
  o.w = (unsigned)f2bf(b.z) | ((unsigned)f2bf(b.w) << 16);
  ((uint4*)xh)[i] = o;
  if (i < TOT_E) {
    int r = i / E_EDGE, e = i - r * E_EDGE;
    int tgt = ei[(r * 2 + 1) * E_EDGE + e];
    atomicAdd(&counts[r * N_ENT + tgt], 1u);
  }
}

// ---- Weights -> bf16 MFMA B-fragment order (blocks 0..287); bias frag (blocks 288..291) ----
__global__ __launch_bounds__(256) void k_cvt_w(const float* __restrict__ relw,
                                               const float* __restrict__ selfw,
                                               const float* __restrict__ bias,
                                               unsigned short* __restrict__ wf,
                                               unsigned short* __restrict__ bb) {
  if (blockIdx.x < 288) {
    int t = blockIdx.x * 256 + threadIdx.x;   // 9*8*16*64 = 73728
    int rel = t >> 13;
    int rem = t & 8191;
    int kb = rem >> 10;
    int nb = (rem >> 6) & 15;
    int lane = rem & 63;
    const float* W = (rel < R_REL) ? (relw + rel * D * D) : selfw;
    int k0 = kb * 32 + (lane >> 4) * 8;
    int n = nb * 16 + (lane & 15);
    unsigned int o[4];
#pragma unroll
    for (int jj = 0; jj < 4; ++jj) {
      unsigned lo = f2bf(W[(k0 + 2 * jj) * D + n]);
      unsigned hi = f2bf(W[(k0 + 2 * jj + 1) * D + n]);
      o[jj] = lo | (hi << 16);
    }
    ((uint4*)wf)[t] = make_uint4(o[0], o[1], o[2], o[3]);
  } else {
    int t = (blockIdx.x - 288) * 256 + threadIdx.x;   // 1024
    int nb = t >> 6, lane = t & 63;
    int lk = lane >> 4, n = nb * 16 + (lane & 15);
    unsigned int o[4];
#pragma unroll
    for (int jj = 0; jj < 4; ++jj) {
      unsigned lo = 0, hi = 0;
      if (lk == 0) {
        lo = f2bf(bias[(2 * jj) * D + n]);
        hi = f2bf(bias[(2 * jj + 1) * D + n]);
      }
      o[jj] = lo | (hi << 16);
    }
    ((uint4*)bb)[t] = make_uint4(o[0], o[1], o[2], o[3]);
  }
}

// ---- exclusive scan (3 kernels) ----
__global__ __launch_bounds__(256) void k_scan1(const unsigned* __restrict__ cnt,
                                               unsigned* __restrict__ off,
                                               unsigned* __restrict__ aux) {
  __shared__ unsigned sc[256];
  int tid = threadIdx.x;
  int base = blockIdx.x * SCAN_B + tid * 4;
  unsigned v[4];
#pragma unroll
  for (int j = 0; j < 4; ++j) v[j] = (base + j < MKEY) ? cnt[base + j] : 0u;
  unsigned s = v[0] + v[1] + v[2] + v[3];
  sc[tid] = s;
  __syncthreads();
  for (int o = 1; o < 256; o <<= 1) {
    unsigned t = (tid >= o) ? sc[tid - o] : 0u;
    __syncthreads();
    sc[tid] += t;
    __syncthreads();
  }
  unsigned excl = sc[tid] - s;
  if (tid == 255) aux[blockIdx.x] = sc[255];
#pragma unroll
  for (int j = 0; j < 4; ++j) {
    if (base + j < MKEY) off[base + j] = excl;
    excl += v[j];
  }
}

__global__ __launch_bounds__(256) void k_scan2(unsigned* __restrict__ aux) {
  __shared__ unsigned sc[256];
  int tid = threadIdx.x;
  int base = tid * 7;
  unsigned v[7];
#pragma unroll
  for (int j = 0; j < 7; ++j) v[j] = (base + j < NBLK_SCAN) ? aux[base + j] : 0u;
  unsigned s = 0;
#pragma unroll
  for (int j = 0; j < 7; ++j) s += v[j];
  sc[tid] = s;
  __syncthreads();
  for (int o = 1; o < 256; o <<= 1) {
    unsigned t = (tid >= o) ? sc[tid - o] : 0u;
    __syncthreads();
    sc[tid] += t;
    __syncthreads();
  }
  unsigned excl = sc[tid] - s;
#pragma unroll
  for (int j = 0; j < 7; ++j) {
    if (base + j < NBLK_SCAN) aux[base + j] = excl;
    excl += v[j];
  }
}

__global__ __launch_bounds__(256) void k_scan3(unsigned* __restrict__ off,
                                               const unsigned* __restrict__ aux) {
  unsigned add = aux[blockIdx.x];
  int base = blockIdx.x * SCAN_B + threadIdx.x * 4;
  if (base + 3 < MKEY) {
    uint4* p = (uint4*)(off + base);
    uint4 x = *p;
    x.x += add; x.y += add; x.z += add; x.w += add;
    *p = x;
  } else {
    for (int j = 0; j < 4; ++j)
      if (base + j < MKEY) off[base + j] += add;
  }
}

// ---- scatter (src | (tgt&63)<<18, ew); off becomes segment ENDs ----
__global__ __launch_bounds__(256) void k_scatter(const int* __restrict__ ei,
                                                 const float* __restrict__ ew,
                                                 unsigned* __restrict__ off,
                                                 unsigned* __restrict__ spack,
                                                 float* __restrict__ sewt) {
  int t = blockIdx.x * 256 + threadIdx.x;
  if (t >= TOT_E) return;
  int r = t / E_EDGE, e = t - r * E_EDGE;
  int tgt = ei[(r * 2 + 1) * E_EDGE + e];
  int src = ei[(r * 2) * E_EDGE + e];
  float w = ew[t];
  unsigned pos = atomicAdd(&off[r * N_ENT + tgt], 1u);
  spack[pos] = (unsigned)src | ((unsigned)(tgt & 63) << 18);
  sewt[pos] = w;
}

// ---- issue 16 gathers for a relation pair (addresses via shfl; pk not kept) ----
__device__ __forceinline__ void agg2_issue(int lane,
                                           unsigned sLo, unsigned eLo, unsigned pkcLo,
                                           unsigned sHi, unsigned eHi, unsigned pkcHi,
                                           const unsigned short* __restrict__ xh,
                                           ushort4 xv[16]) {
  int mLo = (int)(eLo - sLo); mLo = mLo < 8 ? mLo : 8;
  int mHi = (int)(eHi - sHi); mHi = mHi < 8 ? mHi : 8;
#pragma unroll
  for (int u = 0; u < 8; ++u) {
    unsigned pk = (unsigned)__shfl((int)pkcLo, u);
    unsigned srcu = (u < mLo) ? (pk & 0x3FFFFu) : 0u;   // invalid -> row 0 (L1-hot)
    xv[u] = *(const ushort4*)(xh + (size_t)srcu * 256 + lane * 4);
  }
#pragma unroll
  for (int u = 0; u < 8; ++u) {
    unsigned pk = (unsigned)__shfl((int)pkcHi, u);
    unsigned srcu = (u < mHi) ? (pk & 0x3FFFFu) : 0u;
    xv[8 + u] = *(const ushort4*)(xh + (size_t)srcu * 256 + lane * 4);
  }
}

// ---- finish one relation half: run-length accumulate + flush (stride 1024, +halfOff) ----
__device__ __forceinline__ void agg_fin_half(int lane, unsigned s0, unsigned e0,
                                             unsigned pkc, float wtc,
                                             const unsigned* __restrict__ spack,
                                             const float* __restrict__ sewt,
                                             const unsigned short* __restrict__ xh,
                                             unsigned char* As, int halfOff,
                                             const ushort4* xv) {
  int total = (int)(e0 - s0);
  if (total <= 0) return;
  int gp = -1;
  float a0 = 0.f, a1 = 0.f, a2 = 0.f, a3 = 0.f;
#define AGG_FLUSH2() do { \
    unsigned lo_ = (unsigned)f2bf(a0) | ((unsigned)f2bf(a1) << 16); \
    unsigned hi_ = (unsigned)f2bf(a2) | ((unsigned)f2bf(a3) << 16); \
    int wb_ = (gp * 1024 + halfOff + lane * 8) ^ ((gp & 7) << 4); \
    *(uint2*)(As + wb_) = make_uint2(lo_, hi_); } while (0)

  int mch = total < 64 ? total : 64;
  int m0 = mch < 8 ? mch : 8;
  // group 0: gathers prefetched in agg2_issue
#pragma unroll
  for (int u = 0; u < 8; ++u) {
    if (u < m0) {
      unsigned pk = (unsigned)__shfl((int)pkc, u);
      float wt = __shfl(wtc, u);
      int g = (int)(pk >> 18);
      if (g != gp) {
        if (gp >= 0) AGG_FLUSH2();
        a0 = a1 = a2 = a3 = 0.f;
        gp = g;
      }
      a0 += wt * bf2f(xv[u].x);
      a1 += wt * bf2f(xv[u].y);
      a2 += wt * bf2f(xv[u].z);
      a3 += wt * bf2f(xv[u].w);
    }
  }
  // remaining groups of chunk 0 (P(>8 edges per 8-key segment) ~ 15%)
  for (int g8 = 8; g8 < mch; g8 += 8) {
    unsigned q8[8];
    float v8[8];
#pragma unroll
    for (int u = 0; u < 8; ++u) {
      q8[u] = (unsigned)__shfl((int)pkc, g8 + u);
      v8[u] = __shfl(wtc, g8 + u);
    }
    ushort4 yv[8];
#pragma unroll
    for (int u = 0; u < 8; ++u) {
      unsigned srcu = (g8 + u < mch) ? (q8[u] & 0x3FFFFu) : 0u;
      yv[u] = *(const ushort4*)(xh + (size_t)srcu * 256 + lane * 4);
    }
#pragma unroll
    for (int u = 0; u < 8; ++u) {
      if (g8 + u < mch) {
        int g = (int)(q8[u] >> 18);
        if (g != gp) {
          if (gp >= 0) AGG_FLUSH2();
          a0 = a1 = a2 = a3 = 0.f;
          gp = g;
        }
        float wt = v8[u];
        a0 += wt * bf2f(yv[u].x);
        a1 += wt * bf2f(yv[u].y);
        a2 += wt * bf2f(yv[u].z);
        a3 += wt * bf2f(yv[u].w);
      }
    }
  }
  // remaining chunks (very rare: >64 edges)
  for (unsigned chunk = s0 + 64u; chunk < e0; chunk += 64u) {
    unsigned idx = chunk + (unsigned)lane;
    if (idx >= (unsigned)TOT_E) idx = (unsigned)(TOT_E - 1);
    unsigned pkv = spack[idx];
    float wtv = sewt[idx];
    int rem = (int)(e0 - chunk);
    int m = rem < 64 ? rem : 64;
    for (int g8 = 0; g8 < m; g8 += 8) {
      unsigned q8[8];
      float v8[8];
#pragma unroll
      for (int u = 0; u < 8; ++u) {
        q8[u] = (unsigned)__shfl((int)pkv, g8 + u);
        v8[u] = __shfl(wtv, g8 + u);
      }
      ushort4 yv[8];
#pragma unroll
      for (int u = 0; u < 8; ++u) {
        unsigned srcu = (g8 + u < m) ? (q8[u] & 0x3FFFFu) : 0u;
        yv[u] = *(const ushort4*)(xh + (size_t)srcu * 256 + lane * 4);
      }
#pragma unroll
      for (int u = 0; u < 8; ++u) {
        if (g8 + u < m) {
          int g = (int)(q8[u] >> 18);
          if (g != gp) {
            if (gp >= 0) AGG_FLUSH2();
            a0 = a1 = a2 = a3 = 0.f;
            gp = g;
          }
          float wt = v8[u];
          a0 += wt * bf2f(yv[u].x);
          a1 += wt * bf2f(yv[u].y);
          a2 += wt * bf2f(yv[u].z);
          a3 += wt * bf2f(yv[u].w);
        }
      }
    }
  }
  if (gp >= 0) AGG_FLUSH2();
#undef AGG_FLUSH2
}

// ---- fused main: 512 threads / 64 targets, paired-rel phases, As[64][512] bf16 ----
__global__ __launch_bounds__(512, 2) void k_main(const unsigned short* __restrict__ xh,
                                                 const unsigned short* __restrict__ wf,
                                                 const unsigned short* __restrict__ bbf,
                                                 const unsigned* __restrict__ counts,
                                                 const unsigned* __restrict__ off_end,
                                                 const unsigned* __restrict__ spack,
                                                 const float* __restrict__ sewt,
                                                 float* __restrict__ out) {
  __shared__ __align__(16) unsigned char As[64 * 1024];   // [64 rows][512 cols bf16]
  int n0 = blockIdx.x * 64;
  int tid = threadIdx.x;
  int w = tid >> 6, lane = tid & 63;
  int lm = lane & 15, lk = lane >> 4;
  int rbase = (w >> 2) * 32;          // wave's 32-row half for MFMA
  int cbase = (w & 3) * 4;            // wave's 4 nb columns (64 cols)
  int g0 = w * 8;                     // wave's first owned row

  // ---- prefetch 1: all 8 rels' segment bounds (16 independent loads) ----
  unsigned sB[8], eE[8];
#pragma unroll
  for (int r = 0; r < 8; ++r) {
    int kb2 = r * N_ENT + n0 + w * 8;
    sB[r] = kb2 ? off_end[kb2 - 1] : 0u;
    eE[r] = off_end[kb2 + 7];
  }

  f32x4 acc[2][4] = {};

  // ---- self phase (hides meta latency): A-frags direct from global bf16 X ----
  {
    const unsigned short* wfb = wf + 8 * 65536;
#pragma unroll
    for (int kb = 0; kb < 8; ++kb) {
      u16x8 a[2], b[4];
#pragma unroll
      for (int mi = 0; mi < 2; ++mi)
        a[mi] = *(const u16x8*)(xh + (size_t)(n0 + rbase + mi * 16 + lm) * 256 + kb * 32 + lk * 8);
#pragma unroll
      for (int ni = 0; ni < 4; ++ni)
        b[ni] = *(const u16x8*)(wfb + ((kb * 16 + cbase + ni) * 64 + lane) * 8);
#pragma unroll
      for (int mi = 0; mi < 2; ++mi)
#pragma unroll
        for (int ni = 0; ni < 4; ++ni)
          acc[mi][ni] = mfma16(a[mi], b[ni], acc[mi][ni]);
    }
  }

  // ---- prefetch 2: first 64-edge chunk per rel (16 independent loads) ----
  unsigned pk0[8];
  float wt0[8];
#pragma unroll
  for (int r = 0; r < 8; ++r) {
    unsigned idx = sB[r] + (unsigned)lane;
    if (idx >= (unsigned)TOT_E) idx = (unsigned)(TOT_E - 1);
    pk0[r] = spack[idx];
    wt0[r] = sewt[idx];
  }

  f32x4 z4 = {0.f, 0.f, 0.f, 0.f};

  // ---- prologue: aggregate rels 0,1 into As ----
  {
    ushort4 xv[16];
    agg2_issue(lane, sB[0], eE[0], pk0[0], sB[1], eE[1], pk0[1], xh, xv);
#pragma unroll
    for (int k = 0; k < 8; ++k) {
      int g = g0 + k;
      int wb = (g * 1024 + lane * 16) ^ ((g & 7) << 4);
      *(f32x4*)(As + wb) = z4;
    }
    agg_fin_half(lane, sB[0], eE[0], pk0[0], wt0[0], spack, sewt, xh, As, 0, xv);
    agg_fin_half(lane, sB[1], eE[1], pk0[1], wt0[1], spack, sewt, xh, As, 512, xv + 8);
  }
  __syncthreads();

  // ---- 4 paired-relation phases ----
#pragma unroll
  for (int p = 0; p < 4; ++p) {
    ushort4 xv[16];
    if (p < 3)
      agg2_issue(lane, sB[2 * p + 2], eE[2 * p + 2], pk0[2 * p + 2],
                 sB[2 * p + 3], eE[2 * p + 3], pk0[2 * p + 3], xh, xv);

    // MFMA K=512 over rel pair (2p, 2p+1) — covers the just-issued gathers
    const unsigned short* wfbL = wf + (2 * p) * 65536;
    const unsigned short* wfbR = wf + (2 * p + 1) * 65536;
#pragma unroll
    for (int kb2 = 0; kb2 < 16; ++kb2) {
      const unsigned short* wfb = (kb2 < 8) ? wfbL : wfbR;
      int kb = kb2 & 7;
      u16x8 a[2], b[4];
#pragma unroll
      for (int mi = 0; mi < 2; ++mi) {
        int row = rbase + mi * 16 + lm;
        int byt = (row * 1024 + kb2 * 64 + lk * 16) ^ ((row & 7) << 4);
        a[mi] = *(const u16x8*)(As + byt);
      }
#pragma unroll
      for (int ni = 0; ni < 4; ++ni)
        b[ni] = *(const u16x8*)(wfb + ((kb * 16 + cbase + ni) * 64 + lane) * 8);
#pragma unroll
      for (int mi = 0; mi < 2; ++mi)
#pragma unroll
        for (int ni = 0; ni < 4; ++ni)
          acc[mi][ni] = mfma16(a[mi], b[ni], acc[mi][ni]);
    }

    if (p < 3) {
      __syncthreads();   // all MFMA reads of As complete
#pragma unroll
      for (int k = 0; k < 8; ++k) {
        int g = g0 + k;
        int wb = (g * 1024 + lane * 16) ^ ((g & 7) << 4);
        *(f32x4*)(As + wb) = z4;
      }
      agg_fin_half(lane, sB[2 * p + 2], eE[2 * p + 2], pk0[2 * p + 2], wt0[2 * p + 2],
                   spack, sewt, xh, As, 0, xv);
      agg_fin_half(lane, sB[2 * p + 3], eE[2 * p + 3], pk0[2 * p + 3], wt0[2 * p + 3],
                   spack, sewt, xh, As, 512, xv + 8);
      __syncthreads();   // writes done before next MFMA
    }
  }

  // ---- bias via presence MFMA: P[64x8] @ bias[8x256] ----
  {
    u16x8 bb[4];
#pragma unroll
    for (int ni = 0; ni < 4; ++ni)
      bb[ni] = *(const u16x8*)(bbf + ((cbase + ni) * 64 + lane) * 8);
#pragma unroll
    for (int mi = 0; mi < 2; ++mi) {
      u16x8 pa = {};
      if (lk == 0) {
        int n = n0 + rbase + mi * 16 + lm;
#pragma unroll
        for (int r = 0; r < 8; ++r)
          pa[r] = counts[r * N_ENT + n] ? 0x3F80 : 0;
      }
#pragma unroll
      for (int ni = 0; ni < 4; ++ni)
        acc[mi][ni] = mfma16(pa, bb[ni], acc[mi][ni]);
    }
  }

  // ---- epilogue ----
#pragma unroll
  for (int mi = 0; mi < 2; ++mi)
#pragma unroll
    for (int ni = 0; ni < 4; ++ni) {
      int col = (w & 3) * 64 + ni * 16 + lm;
#pragma unroll
      for (int j = 0; j < 4; ++j) {
        int row = n0 + rbase + mi * 16 + lk * 4 + j;
        out[row * 256 + col] = acc[mi][ni][j];
      }
    }
}

extern "C" void kernel_launch(void* const* d_in, const int* in_sizes, int n_in,
                              void* d_out, int out_size, void* d_ws, size_t ws_size,
                              hipStream_t stream) {
  const float* x = (const float*)d_in[0];
  const float* relw = (const float*)d_in[1];
  const float* selfw = (const float*)d_in[2];
  const float* bias = (const float*)d_in[3];
  const int* ei = (const int*)d_in[4];
  const float* ew = (const float*)d_in[5];
  float* out = (float*)d_out;

  char* ws = (char*)d_ws;
  unsigned short* xh = (unsigned short*)ws;                          // 102,400,000
  unsigned short* wf = (unsigned short*)(ws + 102400000);            //   1,179,648
  unsigned short* bbf = (unsigned short*)(ws + 103579648);           //      16,384
  unsigned* counts = (unsigned*)(ws + 103596032);                    //   6,400,000
  unsigned* offs = (unsigned*)(ws + 109996032);                      //   6,400,000
  unsigned* aux = (unsigned*)(ws + 116396032);                       //       8,192
  unsigned* spack = (unsigned*)(ws + 116404224);                     //   4,800,000
  float* sewt = (float*)(ws + 121204224);                            //   4,800,000

  hipMemsetAsync(counts, 0, (size_t)MKEY * 4, stream);
  k_cvt_x<<<(N_ENT * D) / 2048, 256, 0, stream>>>(x, xh, ei, counts);   // + fused hist
  k_cvt_w<<<292, 256, 0, stream>>>(relw, selfw, bias, wf, bbf);         // + fused bias cvt
  k_scan1<<<NBLK_SCAN, 256, 0, stream>>>(counts, offs, aux);
  k_scan2<<<1, 256, 0, stream>>>(aux);
  k_scan3<<<NBLK_SCAN, 256, 0, stream>>>(offs, aux);
  k_scatter<<<(TOT_E + 255) / 256, 256, 0, stream>>>(ei, ew, offs, spack, sewt);
  k_main<<<N_ENT / 64, 512, 0, stream>>>(xh, wf, bbf, counts, offs, spack, sewt, out);
}

// Round 16
// 695.224 us; speedup vs baseline: 1.4396x; 1.0513x over previous
//
#include <hip/hip_runtime.h>

// WRGCN: out[t] = sum_r (sum_{e:tgt=t,rel=r} ew_e * X[src_e]) @ W_r + X[t] @ W_self + P @ bias
// Counting-sort edges by key = r*N + tgt. k_main: 256 thr / 32 targets; wave w owns keys
// [n0+8w, n0+8w+8). Double-buffered As (2x16KB), merged phases (issue next rel's gathers ->
// MFMA current -> finish agg -> ONE barrier). 32KB LDS + ~100 VGPR -> 4-5 blocks/CU =
// 4-5 independent barrier groups (vs 2 at 512thr/64KB): cross-group overlap fills stalls.
// VGPR RULE (r5/r12/r14): __launch_bounds__(B,N) caps VGPR at 256/N. N=4 -> 64 = fatal
// spills (FETCH/WRITE blow up 3-4x). Use N=2 (128 cap); kernel needs ~100-120.

#define N_ENT 200000
#define D 256
#define R_REL 8
#define E_EDGE 150000
#define TOT_E (R_REL * E_EDGE)        // 1,200,000
#define MKEY (N_ENT * R_REL)          // 1,600,000
#define SCAN_B 1024
#define NBLK_SCAN ((MKEY + SCAN_B - 1) / SCAN_B)   // 1563

typedef __bf16 bf16x8 __attribute__((ext_vector_type(8)));
typedef unsigned short u16x8 __attribute__((ext_vector_type(8)));
typedef float f32x4 __attribute__((ext_vector_type(4)));

__device__ __forceinline__ unsigned short f2bf(float f) {
  unsigned int u = __builtin_bit_cast(unsigned int, f);
  u += 0x7FFFu + ((u >> 16) & 1u);   // RNE (inputs finite)
  return (unsigned short)(u >> 16);
}
__device__ __forceinline__ float bf2f(unsigned short u) {
  return __builtin_bit_cast(float, ((unsigned)u) << 16);
}
__device__ __forceinline__ f32x4 mfma16(u16x8 a, u16x8 b, f32x4 c) {
  return __builtin_amdgcn_mfma_f32_16x16x32_bf16(
      __builtin_bit_cast(bf16x8, a), __builtin_bit_cast(bf16x8, b), c, 0, 0, 0);
}

// ---- X (f32) -> Xh (bf16), fused with edge-target histogram ----
__global__ __launch_bounds__(256) void k_cvt_x(const float* __restrict__ x,
                                               unsigned short* __restrict__ xh,
                                               const int* __restrict__ ei,
                                               unsigned* __restrict__ counts) {
  int i = blockIdx.x * 256 + threadIdx.x;
  const float4* xv = (const float4*)x;
  float4 a = xv[2 * i], b = xv[2 * i + 1];
  uint4 o;
  o.x = (unsigned)f2bf(a.x) | ((unsigned)f2bf(a.y) << 16);
  o.y = (unsigned)f2bf(a.z) | ((unsigned)f2bf(a.w) << 16);
  o.z = (unsigned)f2bf(b.x) | ((unsigned)f2bf(b.y) << 16);
  o.w = (unsigned)f2bf(b.z) | ((unsigned)f2bf(b.w) << 16);
  ((uint4*)xh)[i] = o;
  if (i < TOT_E) {
    int r = i / E_EDGE, e = i - r * E_EDGE;
    int tgt = ei[(r * 2 + 1) * E_EDGE + e];
    atomicAdd(&counts[r * N_ENT + tgt], 1u);
  }
}

// ---- Weights -> bf16 MFMA B-fragment order (blocks 0..287); bias frag (blocks 288..291) ----
__global__ __launch_bounds__(256) void k_cvt_w(const float* __restrict__ relw,
                                               const float* __restrict__ selfw,
                                               const float* __restrict__ bias,
                                               unsigned short* __restrict__ wf,
                                               unsigned short* __restrict__ bb) {
  if (blockIdx.x < 288) {
    int t = blockIdx.x * 256 + threadIdx.x;   // 9*8*16*64 = 73728
    int rel = t >> 13;
    int rem = t & 8191;
    int kb = rem >> 10;
    int nb = (rem >> 6) & 15;
    int lane = rem & 63;
    const float* W = (rel < R_REL) ? (relw + rel * D * D) : selfw;
    int k0 = kb * 32 + (lane >> 4) * 8;
    int n = nb * 16 + (lane & 15);
    unsigned int o[4];
#pragma unroll
    for (int jj = 0; jj < 4; ++jj) {
      unsigned lo = f2bf(W[(k0 + 2 * jj) * D + n]);
      unsigned hi = f2bf(W[(k0 + 2 * jj + 1) * D + n]);
      o[jj] = lo | (hi << 16);
    }
    ((uint4*)wf)[t] = make_uint4(o[0], o[1], o[2], o[3]);
  } else {
    int t = (blockIdx.x - 288) * 256 + threadIdx.x;   // 1024
    int nb = t >> 6, lane = t & 63;
    int lk = lane >> 4, n = nb * 16 + (lane & 15);
    unsigned int o[4];
#pragma unroll
    for (int jj = 0; jj < 4; ++jj) {
      unsigned lo = 0, hi = 0;
      if (lk == 0) {
        lo = f2bf(bias[(2 * jj) * D + n]);
        hi = f2bf(bias[(2 * jj + 1) * D + n]);
      }
      o[jj] = lo | (hi << 16);
    }
    ((uint4*)bb)[t] = make_uint4(o[0], o[1], o[2], o[3]);
  }
}

// ---- exclusive scan (3 kernels) ----
__global__ __launch_bounds__(256) void k_scan1(const unsigned* __restrict__ cnt,
                                               unsigned* __restrict__ off,
                                               unsigned* __restrict__ aux) {
  __shared__ unsigned sc[256];
  int tid = threadIdx.x;
  int base = blockIdx.x * SCAN_B + tid * 4;
  unsigned v[4];
#pragma unroll
  for (int j = 0; j < 4; ++j) v[j] = (base + j < MKEY) ? cnt[base + j] : 0u;
  unsigned s = v[0] + v[1] + v[2] + v[3];
  sc[tid] = s;
  __syncthreads();
  for (int o = 1; o < 256; o <<= 1) {
    unsigned t = (tid >= o) ? sc[tid - o] : 0u;
    __syncthreads();
    sc[tid] += t;
    __syncthreads();
  }
  unsigned excl = sc[tid] - s;
  if (tid == 255) aux[blockIdx.x] = sc[255];
#pragma unroll
  for (int j = 0; j < 4; ++j) {
    if (base + j < MKEY) off[base + j] = excl;
    excl += v[j];
  }
}

__global__ __launch_bounds__(256) void k_scan2(unsigned* __restrict__ aux) {
  __shared__ unsigned sc[256];
  int tid = threadIdx.x;
  int base = tid * 7;
  unsigned v[7];
#pragma unroll
  for (int j = 0; j < 7; ++j) v[j] = (base + j < NBLK_SCAN) ? aux[base + j] : 0u;
  unsigned s = 0;
#pragma unroll
  for (int j = 0; j < 7; ++j) s += v[j];
  sc[tid] = s;
  __syncthreads();
  for (int o = 1; o < 256; o <<= 1) {
    unsigned t = (tid >= o) ? sc[tid - o] : 0u;
    __syncthreads();
    sc[tid] += t;
    __syncthreads();
  }
  unsigned excl = sc[tid] - s;
#pragma unroll
  for (int j = 0; j < 7; ++j) {
    if (base + j < NBLK_SCAN) aux[base + j] = excl;
    excl += v[j];
  }
}

__global__ __launch_bounds__(256) void k_scan3(unsigned* __restrict__ off,
                                               const unsigned* __restrict__ aux) {
  unsigned add = aux[blockIdx.x];
  int base = blockIdx.x * SCAN_B + threadIdx.x * 4;
  if (base + 3 < MKEY) {
    uint4* p = (uint4*)(off + base);
    uint4 x = *p;
    x.x += add; x.y += add; x.z += add; x.w += add;
    *p = x;
  } else {
    for (int j = 0; j < 4; ++j)
      if (base + j < MKEY) off[base + j] += add;
  }
}

// ---- scatter (src | (tgt&63)<<18, ew); off becomes segment ENDs ----
__global__ __launch_bounds__(256) void k_scatter(const int* __restrict__ ei,
                                                 const float* __restrict__ ew,
                                                 unsigned* __restrict__ off,
                                                 unsigned* __restrict__ spack,
                                                 float* __restrict__ sewt) {
  int t = blockIdx.x * 256 + threadIdx.x;
  if (t >= TOT_E) return;
  int r = t / E_EDGE, e = t - r * E_EDGE;
  int tgt = ei[(r * 2 + 1) * E_EDGE + e];
  int src = ei[(r * 2) * E_EDGE + e];
  float w = ew[t];
  unsigned pos = atomicAdd(&off[r * N_ENT + tgt], 1u);
  spack[pos] = (unsigned)src | ((unsigned)(tgt & 63) << 18);
  sewt[pos] = w;
}

// ---- aggregation helpers (wave-local, run-length over sorted contiguous range) ----
// local row g = (pk >> 18) & 31  (block owns 32 targets, n0 % 32 == 0)
__device__ __forceinline__ void agg_issue(int g0, int lane, unsigned s0, unsigned e0,
                                          unsigned pkc, float wtc,
                                          const unsigned short* __restrict__ xh,
                                          unsigned char* nxt,
                                          unsigned pk8[8], float wt8[8], ushort4 xv[8]) {
  // zero my 8 rows (flushes overwrite later; same-lane LDS ops are ordered)
#pragma unroll
  for (int k = 0; k < 8; ++k) {
    int g = g0 + k;
    int wb = (g * 512 + lane * 8) ^ ((g & 7) << 4);
    *(uint2*)(nxt + wb) = make_uint2(0u, 0u);
  }
  int total = (int)(e0 - s0);
  int m0 = total < 8 ? total : 8;
#pragma unroll
  for (int u = 0; u < 8; ++u) {
    pk8[u] = (unsigned)__shfl((int)pkc, u);
    wt8[u] = __shfl(wtc, u);
  }
#pragma unroll
  for (int u = 0; u < 8; ++u) {
    unsigned srcu = (u < m0) ? (pk8[u] & 0x3FFFFu) : 0u;   // invalid -> row 0 (L1-hot)
    xv[u] = *(const ushort4*)(xh + (size_t)srcu * 256 + lane * 4);
  }
}

__device__ __forceinline__ void agg_finish(int lane, unsigned s0, unsigned e0,
                                           unsigned pkc, float wtc,
                                           const unsigned* __restrict__ spack,
                                           const float* __restrict__ sewt,
                                           const unsigned short* __restrict__ xh,
                                           unsigned char* nxt,
                                           const unsigned pk8[8], const float wt8[8],
                                           const ushort4 xv[8]) {
  int total = (int)(e0 - s0);
  if (total <= 0) return;
  int gp = -1;
  float a0 = 0.f, a1 = 0.f, a2 = 0.f, a3 = 0.f;
#define AGG_FLUSH() do { \
    unsigned lo_ = (unsigned)f2bf(a0) | ((unsigned)f2bf(a1) << 16); \
    unsigned hi_ = (unsigned)f2bf(a2) | ((unsigned)f2bf(a3) << 16); \
    int wb_ = (gp * 512 + lane * 8) ^ ((gp & 7) << 4); \
    *(uint2*)(nxt + wb_) = make_uint2(lo_, hi_); } while (0)

  int mch = total < 64 ? total : 64;
  int m0 = mch < 8 ? mch : 8;
  // group 0: prefetched in agg_issue
#pragma unroll
  for (int u = 0; u < 8; ++u) {
    if (u < m0) {
      int g = (int)((pk8[u] >> 18) & 31u);
      if (g != gp) {
        if (gp >= 0) AGG_FLUSH();
        a0 = a1 = a2 = a3 = 0.f;
        gp = g;
      }
      float wt = wt8[u];
      a0 += wt * bf2f(xv[u].x);
      a1 += wt * bf2f(xv[u].y);
      a2 += wt * bf2f(xv[u].z);
      a3 += wt * bf2f(xv[u].w);
    }
  }
  // remaining groups of chunk 0 (rare: >8 edges in an 8-key segment)
  for (int g8 = 8; g8 < mch; g8 += 8) {
    unsigned q8[8];
    float v8[8];
#pragma unroll
    for (int u = 0; u < 8; ++u) {
      q8[u] = (unsigned)__shfl((int)pkc, g8 + u);
      v8[u] = __shfl(wtc, g8 + u);
    }
    ushort4 yv[8];
#pragma unroll
    for (int u = 0; u < 8; ++u) {
      unsigned srcu = (g8 + u < mch) ? (q8[u] & 0x3FFFFu) : 0u;
      yv[u] = *(const ushort4*)(xh + (size_t)srcu * 256 + lane * 4);
    }
#pragma unroll
    for (int u = 0; u < 8; ++u) {
      if (g8 + u < mch) {
        int g = (int)((q8[u] >> 18) & 31u);
        if (g != gp) {
          if (gp >= 0) AGG_FLUSH();
          a0 = a1 = a2 = a3 = 0.f;
          gp = g;
        }
        float wt = v8[u];
        a0 += wt * bf2f(yv[u].x);
        a1 += wt * bf2f(yv[u].y);
        a2 += wt * bf2f(yv[u].z);
        a3 += wt * bf2f(yv[u].w);
      }
    }
  }
  // remaining chunks (very rare: >64 edges)
  for (unsigned chunk = s0 + 64u; chunk < e0; chunk += 64u) {
    unsigned idx = chunk + (unsigned)lane;
    if (idx >= (unsigned)TOT_E) idx = (unsigned)(TOT_E - 1);
    unsigned pkv = spack[idx];
    float wtv = sewt[idx];
    int rem = (int)(e0 - chunk);
    int m = rem < 64 ? rem : 64;
    for (int g8 = 0; g8 < m; g8 += 8) {
      unsigned q8[8];
      float v8[8];
#pragma unroll
      for (int u = 0; u < 8; ++u) {
        q8[u] = (unsigned)__shfl((int)pkv, g8 + u);
        v8[u] = __shfl(wtv, g8 + u);
      }
      ushort4 yv[8];
#pragma unroll
      for (int u = 0; u < 8; ++u) {
        unsigned srcu = (g8 + u < m) ? (q8[u] & 0x3FFFFu) : 0u;
        yv[u] = *(const ushort4*)(xh + (size_t)srcu * 256 + lane * 4);
      }
#pragma unroll
      for (int u = 0; u < 8; ++u) {
        if (g8 + u < m) {
          int g = (int)((q8[u] >> 18) & 31u);
          if (g != gp) {
            if (gp >= 0) AGG_FLUSH();
            a0 = a1 = a2 = a3 = 0.f;
            gp = g;
          }
          float wt = v8[u];
          a0 += wt * bf2f(yv[u].x);
          a1 += wt * bf2f(yv[u].y);
          a2 += wt * bf2f(yv[u].z);
          a3 += wt * bf2f(yv[u].w);
        }
      }
    }
  }
  if (gp >= 0) AGG_FLUSH();
#undef AGG_FLUSH
}

// ---- fused main: 256 threads / 32 targets, double-buffered As, 1 barrier/rel ----
__global__ __launch_bounds__(256, 2) void k_main(const unsigned short* __restrict__ xh,
                                                 const unsigned short* __restrict__ wf,
                                                 const unsigned short* __restrict__ bbf,
                                                 const unsigned* __restrict__ counts,
                                                 const unsigned* __restrict__ off_end,
                                                 const unsigned* __restrict__ spack,
                                                 const float* __restrict__ sewt,
                                                 float* __restrict__ out) {
  __shared__ __align__(16) unsigned char As[2 * 16384];   // double-buffered 32x256 bf16
  int n0 = blockIdx.x * 32;
  int tid = threadIdx.x;
  int w = tid >> 6, lane = tid & 63;
  int lm = lane & 15, lk = lane >> 4;
  int cbase = w * 4;                  // wave's 4 nb columns (64 cols); rows: all 32
  int g0 = w * 8;                     // wave's first owned row

  // ---- prefetch 1: all 8 rels' segment bounds (16 independent loads) ----
  unsigned sB[8], eE[8];
#pragma unroll
  for (int r = 0; r < 8; ++r) {
    int kb2 = r * N_ENT + n0 + w * 8;
    sB[r] = kb2 ? off_end[kb2 - 1] : 0u;
    eE[r] = off_end[kb2 + 7];
  }

  f32x4 acc[2][4] = {};

  // ---- self phase (hides meta latency): A-frags direct from global bf16 X ----
  {
    const unsigned short* wfb = wf + 8 * 65536;
#pragma unroll
    for (int kb = 0; kb < 8; ++kb) {
      u16x8 a[2], b[4];
#pragma unroll
      for (int mi = 0; mi < 2; ++mi)
        a[mi] = *(const u16x8*)(xh + (size_t)(n0 + mi * 16 + lm) * 256 + kb * 32 + lk * 8);
#pragma unroll
      for (int ni = 0; ni < 4; ++ni)
        b[ni] = *(const u16x8*)(wfb + ((kb * 16 + cbase + ni) * 64 + lane) * 8);
#pragma unroll
      for (int mi = 0; mi < 2; ++mi)
#pragma unroll
        for (int ni = 0; ni < 4; ++ni)
          acc[mi][ni] = mfma16(a[mi], b[ni], acc[mi][ni]);
    }
  }

  // ---- prefetch 2: first 64-edge chunk per rel (16 independent loads) ----
  unsigned pk0[8];
  float wt0[8];
#pragma unroll
  for (int r = 0; r < 8; ++r) {
    unsigned idx = sB[r] + (unsigned)lane;
    if (idx >= (unsigned)TOT_E) idx = (unsigned)(TOT_E - 1);
    pk0[r] = spack[idx];
    wt0[r] = sewt[idx];
  }

  // ---- prologue: aggregate rel 0 into As[0] ----
  {
    unsigned pk8[8];
    float wt8[8];
    ushort4 xv[8];
    agg_issue(g0, lane, sB[0], eE[0], pk0[0], wt0[0], xh, As, pk8, wt8, xv);
    agg_finish(lane, sB[0], eE[0], pk0[0], wt0[0], spack, sewt, xh, As, pk8, wt8, xv);
  }
  __syncthreads();

  // ---- pipelined rel loop: one barrier per rel ----
#pragma unroll
  for (int r = 0; r < 8; ++r) {
    unsigned char* cur = As + (r & 1) * 16384;
    unsigned char* nxt = As + ((r + 1) & 1) * 16384;
    unsigned pk8[8];
    float wt8[8];
    ushort4 xv[8];
    if (r < 7)
      agg_issue(g0, lane, sB[r + 1], eE[r + 1], pk0[r + 1], wt0[r + 1], xh, nxt, pk8, wt8, xv);

    // MFMA(r) from cur — hides the just-issued gathers
    const unsigned short* wfb = wf + r * 65536;
#pragma unroll
    for (int kb = 0; kb < 8; ++kb) {
      u16x8 a[2], b[4];
#pragma unroll
      for (int mi = 0; mi < 2; ++mi) {
        int row = mi * 16 + lm;
        int byt = (row * 512 + kb * 64 + lk * 16) ^ ((row & 7) << 4);
        a[mi] = *(const u16x8*)(cur + byt);
      }
#pragma unroll
      for (int ni = 0; ni < 4; ++ni)
        b[ni] = *(const u16x8*)(wfb + ((kb * 16 + cbase + ni) * 64 + lane) * 8);
#pragma unroll
      for (int mi = 0; mi < 2; ++mi)
#pragma unroll
        for (int ni = 0; ni < 4; ++ni)
          acc[mi][ni] = mfma16(a[mi], b[ni], acc[mi][ni]);
    }

    if (r < 7)
      agg_finish(lane, sB[r + 1], eE[r + 1], pk0[r + 1], wt0[r + 1], spack, sewt, xh, nxt,
                 pk8, wt8, xv);
    __syncthreads();
  }

  // ---- bias via presence MFMA: P[32x8] @ bias[8x256] ----
  {
    u16x8 bb[4];
#pragma unroll
    for (int ni = 0; ni < 4; ++ni)
      bb[ni] = *(const u16x8*)(bbf + ((cbase + ni) * 64 + lane) * 8);
#pragma unroll
    for (int mi = 0; mi < 2; ++mi) {
      u16x8 pa = {};
      if (lk == 0) {
        int n = n0 + mi * 16 + lm;
#pragma unroll
        for (int r = 0; r < 8; ++r)
          pa[r] = counts[r * N_ENT + n] ? 0x3F80 : 0;
      }
#pragma unroll
      for (int ni = 0; ni < 4; ++ni)
        acc[mi][ni] = mfma16(pa, bb[ni], acc[mi][ni]);
    }
  }

  // ---- epilogue ----
#pragma unroll
  for (int mi = 0; mi < 2; ++mi)
#pragma unroll
    for (int ni = 0; ni < 4; ++ni) {
      int col = (cbase + ni) * 16 + lm;
#pragma unroll
      for (int j = 0; j < 4; ++j) {
        int row = n0 + mi * 16 + lk * 4 + j;
        out[row * 256 + col] = acc[mi][ni][j];
      }
    }
}

extern "C" void kernel_launch(void* const* d_in, const int* in_sizes, int n_in,
                              void* d_out, int out_size, void* d_ws, size_t ws_size,
                              hipStream_t stream) {
  const float* x = (const float*)d_in[0];
  const float* relw = (const float*)d_in[1];
  const float* selfw = (const float*)d_in[2];
  const float* bias = (const float*)d_in[3];
  const int* ei = (const int*)d_in[4];
  const float* ew = (const float*)d_in[5];
  float* out = (float*)d_out;

  char* ws = (char*)d_ws;
  unsigned short* xh = (unsigned short*)ws;                          // 102,400,000
  unsigned short* wf = (unsigned short*)(ws + 102400000);            //   1,179,648
  unsigned short* bbf = (unsigned short*)(ws + 103579648);           //      16,384
  unsigned* counts = (unsigned*)(ws + 103596032);                    //   6,400,000
  unsigned* offs = (unsigned*)(ws + 109996032);                      //   6,400,000
  unsigned* aux = (unsigned*)(ws + 116396032);                       //       8,192
  unsigned* spack = (unsigned*)(ws + 116404224);                     //   4,800,000
  float* sewt = (float*)(ws + 121204224);                            //   4,800,000

  hipMemsetAsync(counts, 0, (size_t)MKEY * 4, stream);
  k_cvt_x<<<(N_ENT * D) / 2048, 256, 0, stream>>>(x, xh, ei, counts);   // + fused hist
  k_cvt_w<<<292, 256, 0, stream>>>(relw, selfw, bias, wf, bbf);         // + fused bias cvt
  k_scan1<<<NBLK_SCAN, 256, 0, stream>>>(counts, offs, aux);
  k_scan2<<<1, 256, 0, stream>>>(aux);
  k_scan3<<<NBLK_SCAN, 256, 0, stream>>>(offs, aux);
  k_scatter<<<(TOT_E + 255) / 256, 256, 0, stream>>>(ei, ew, offs, spack, sewt);
  k_main<<<N_ENT / 32, 256, 0, stream>>>(xh, wf, bbf, counts, offs, spack, sewt, out);
}